// Round 8
// baseline (225.271 us; speedup 1.0000x reference)
//
#include <hip/hip_runtime.h>

#define NLOC  10
#define NGI   13
#define NPAIR 55
#define EPB   32           // elements per block
#define TPB   128          // 2 waves; 4 threads per element

// LDS float offsets
#define W_DW   8320        // EPB*260 nx floats before this
#define W_N    8736        // +EPB*13
#define W_TOT  8866        // 35464 B -> 4 blocks/CU

#define NX_GRAN  2080      // 16B granules in nx region (8320/4)
#define TOT_GRAN 2184      // + 104 dw granules

typedef float vf2 __attribute__((ext_vector_type(2)));

__device__ __forceinline__ constexpr int pidx(int i, int j) {   // requires i<=j
    return i * NLOC - (i * (i - 1)) / 2 + (j - i);
}

// async global->LDS, 16B/lane; lds base wave-uniform, HW adds lane*16
__device__ __forceinline__ void stage16(const float* gsrc, float* lds) {
    __builtin_amdgcn_global_load_lds(
        (const __attribute__((address_space(1))) void*)gsrc,
        (__attribute__((address_space(3))) void*)lds, 16, 0, 0);
}

// cross-lane quad permute via DPP (VALU pipe — avoids LDS-pipe ds_swizzle)
// xor1 = quad_perm[1,0,3,2] = 0xB1 ; xor2 = quad_perm[2,3,0,1] = 0x4E
template <int CTRL>
__device__ __forceinline__ float qperm(float x) {
    int r = __builtin_amdgcn_update_dpp(
        0, __builtin_bit_cast(int, x), CTRL, 0xF, 0xF, true);
    return __builtin_bit_cast(float, r);
}

__global__ __launch_bounds__(TPB) void fem_kernel(
    const float* __restrict__ r0g,
    const float* __restrict__ cig,
    const float* __restrict__ cng,
    const float* __restrict__ kp,
    const float* __restrict__ dtp,
    const float* __restrict__ nmat,
    const float* __restrict__ nx,
    const float* __restrict__ dwei,
    float* __restrict__ out,
    int nele)
{
    __shared__ float sm[W_TOT];

    const int  t   = threadIdx.x;
    const long e0  = (long)blockIdx.x * EPB;
    const int  rem = min(EPB, nele - (int)e0);

    // ---------------- stage: flat coalesced granule copy (nx, dw) --------
    const float* nxsrc = nx   + (size_t)e0 * 260;
    const float* dwsrc = dwei + (size_t)e0 * 13;
    const int capnx = rem * 260;
    const int capdw = rem * 13;
    float* ldsb = sm + (t >> 6) * 256;   // per-wave uniform base (floats)
    #pragma unroll
    for (int k = 0; k < 18; ++k) {
        const int G = k * 128 + t;       // granule index; LDS float off = G*4
        if (G < NX_GRAN) {
            if (G * 4 < capnx) stage16(nxsrc + (size_t)G * 4, ldsb + k * 512);
        } else if (G < TOT_GRAN) {
            const int rel = G - NX_GRAN;
            if (rel * 4 < capdw) stage16(dwsrc + (size_t)rel * 4, ldsb + k * 512);
        }
    }
    for (int w = t; w < 130; w += TPB) sm[W_N + w] = nmat[w];

    // per-element thread roles (computed pre-barrier so global loads issue early)
    const int  eloc = t >> 2;
    const int  d    = (t >> 1) & 1;      // spatial dim (stiffness)
    const int  h    = t & 1;             // g-parity (stiffness)
    const int  q    = t & 3;             // g-stride-4 slot (mass, epilogue)
    const long e    = e0 + eloc;
    const bool live = eloc < rem;
    const long ee   = live ? e : (long)(nele - 1);   // clamp for global reads

    const float kk  = kp[0];
    const float idt = 1.0f / dtp[0];

    // hoisted global loads: overlap HBM latency with the stage drain
    float civ[NLOC], dif[NLOC];
    {
        const vf2* ci2 = reinterpret_cast<const vf2*>(cig + (size_t)ee * 10);
        const vf2* cn2 = reinterpret_cast<const vf2*>(cng + (size_t)ee * 10);
        #pragma unroll
        for (int u2 = 0; u2 < 5; ++u2) {
            vf2 a = ci2[u2], b = cn2[u2];
            civ[2*u2]   = a.x; civ[2*u2+1] = a.y;
            dif[2*u2]   = b.x - a.x; dif[2*u2+1] = b.y - a.y;
        }
    }

    __syncthreads();                     // drains vmcnt for global_load_lds

    const float* smnx = sm + eloc * 260 + d * 130;
    const float* smdw = sm + W_DW + eloc * 13;
    const float* smn  = sm + W_N;

    float acc[NPAIR];
    #pragma unroll
    for (int p = 0; p < NPAIR; ++p) acc[p] = 0.0f;
    float r0a[NLOC];
    #pragma unroll
    for (int i = 0; i < NLOC; ++i) r0a[i] = 0.0f;

    // stiffness: this thread's dim d, g = 2*it + h (7 iters, last guarded)
    #pragma unroll
    for (int it = 0; it < 7; ++it) {
        const int   graw = 2 * it + h;
        const int   g    = graw < NGI ? graw : NGI - 1;
        const float wv   = graw < NGI ? kk * smdw[g] : 0.0f;
        float col[NLOC];
        #pragma unroll
        for (int l = 0; l < NLOC; ++l) col[l] = smnx[l * 13 + g];
        float u = 0.0f;
        #pragma unroll
        for (int l = 0; l < NLOC; ++l) u = fmaf(col[l], civ[l], u);
        const float uw = u * wv;
        #pragma unroll
        for (int i = 0; i < NLOC; ++i) {
            const float ti = col[i] * wv;
            #pragma unroll
            for (int j = i; j < NLOC; ++j)
                acc[pidx(i, j)] = fmaf(ti, col[j], acc[pidx(i, j)]);
            r0a[i] = fmaf(-col[i], uw, r0a[i]);
        }
    }

    // mass: g = q + 4*it (4 iters, guarded); weight idt*dw; r0 += nn/dt*(cn-ci)
    #pragma unroll
    for (int it = 0; it < 4; ++it) {
        const int   graw = q + 4 * it;
        const int   g    = graw < NGI ? graw : NGI - 1;
        const float wv   = graw < NGI ? idt * smdw[g] : 0.0f;
        float ncol[NLOC];
        #pragma unroll
        for (int l = 0; l < NLOC; ++l) ncol[l] = smn[l * 13 + g];
        float wd = 0.0f;
        #pragma unroll
        for (int l = 0; l < NLOC; ++l) wd = fmaf(ncol[l], dif[l], wd);
        #pragma unroll
        for (int i = 0; i < NLOC; ++i) {
            const float ti = ncol[i] * wv;
            #pragma unroll
            for (int j = i; j < NLOC; ++j)
                acc[pidx(i, j)] = fmaf(ti, ncol[j], acc[pidx(i, j)]);
            r0a[i] = fmaf(ti, wd, r0a[i]);
        }
    }

    // combine the 4 partial sums: DPP quad butterfly (VALU, no LDS traffic)
    #pragma unroll
    for (int p = 0; p < NPAIR; ++p) {
        acc[p] += qperm<0xB1>(acc[p]);
        acc[p] += qperm<0x4E>(acc[p]);
    }
    #pragma unroll
    for (int i = 0; i < NLOC; ++i) {
        r0a[i] += qperm<0xB1>(r0a[i]);
        r0a[i] += qperm<0x4E>(r0a[i]);
    }

    // ---------------- epilogue: rows split by (i&3)==q, literal indices --
    if (live) {
        float* obd = out + (size_t)e * 100;
        float* odg = out + (size_t)nele * 100 + (size_t)e * 10;
        float* oro = out + (size_t)nele * 110 + (size_t)e * 10;
        const float* r0s = r0g + (size_t)e * 10;
        #pragma unroll
        for (int i = 0; i < NLOC; ++i) {
            if ((i & 3) == q) {
                float row[NLOC];
                #pragma unroll
                for (int j = 0; j < NLOC; ++j) {
                    const int lo = i < j ? i : j, hi = i < j ? j : i;
                    row[j] = acc[pidx(lo, hi)];
                }
                #pragma unroll
                for (int u2 = 0; u2 < 5; ++u2) {
                    vf2 v = { row[2*u2], row[2*u2+1] };
                    *reinterpret_cast<vf2*>(obd + i * 10 + 2 * u2) = v;
                }
                odg[i] = row[i];
                oro[i] = r0s[i] + r0a[i];
            }
        }
    }
}

extern "C" void kernel_launch(void* const* d_in, const int* in_sizes, int n_in,
                              void* d_out, int out_size, void* d_ws, size_t ws_size,
                              hipStream_t stream) {
    const float* r0   = (const float*)d_in[0];
    const float* ci   = (const float*)d_in[1];
    const float* cn   = (const float*)d_in[2];
    const float* k    = (const float*)d_in[3];
    const float* dt   = (const float*)d_in[4];
    const float* nmat = (const float*)d_in[5];
    const float* nx   = (const float*)d_in[6];
    const float* dw   = (const float*)d_in[7];
    const int nele = in_sizes[7] / NGI;

    const int nb = (nele + EPB - 1) / EPB;
    fem_kernel<<<nb, TPB, 0, stream>>>(r0, ci, cn, k, dt, nmat, nx, dw,
                                       (float*)d_out, nele);
}

// Round 9
// 219.905 us; speedup vs baseline: 1.0244x; 1.0244x over previous
//
#include <hip/hip_runtime.h>

#define NLOC  10
#define NGI   13
#define NPAIR 55
#define EPB   64           // elements per block
#define TPB   256          // 4 waves; 4 threads per element

// LDS float offsets
#define W_NX   0           // EPB*260 = 16640 floats
#define W_DW   16640       // EPB*13  = 832 floats
#define W_N    17472       // 130 floats (shape-function table)
#define W_TOT  17604       // 70416 B -> 2 blocks/CU

#define NX_GRAN  4160      // 16B granules in nx region (16640/4)
#define TOT_GRAN 4368      // + 208 dw granules

typedef float vf2 __attribute__((ext_vector_type(2)));

__device__ __forceinline__ constexpr int pidx(int i, int j) {   // requires i<=j
    return i * NLOC - (i * (i - 1)) / 2 + (j - i);
}

// async global->LDS, 16B/lane; lds base wave-uniform, HW adds lane*16
__device__ __forceinline__ void stage16(const float* gsrc, float* lds) {
    __builtin_amdgcn_global_load_lds(
        (const __attribute__((address_space(1))) void*)gsrc,
        (__attribute__((address_space(3))) void*)lds, 16, 0, 0);
}

// cross-lane quad permute via DPP (VALU pipe — keeps butterfly off the LDS pipe)
// xor1 = quad_perm[1,0,3,2] = 0xB1 ; xor2 = quad_perm[2,3,0,1] = 0x4E
template <int CTRL>
__device__ __forceinline__ float qperm(float x) {
    int r = __builtin_amdgcn_update_dpp(
        0, __builtin_bit_cast(int, x), CTRL, 0xF, 0xF, true);
    return __builtin_bit_cast(float, r);
}

__global__ __launch_bounds__(TPB) void fem_kernel(
    const float* __restrict__ r0g,
    const float* __restrict__ cig,
    const float* __restrict__ cng,
    const float* __restrict__ kp,
    const float* __restrict__ dtp,
    const float* __restrict__ nmat,
    const float* __restrict__ nx,
    const float* __restrict__ dwei,
    float* __restrict__ out,
    int nele)
{
    __shared__ float sm[W_TOT];

    const int  t   = threadIdx.x;
    const long e0  = (long)blockIdx.x * EPB;
    const int  rem = min(EPB, nele - (int)e0);

    // ---------------- stage: flat coalesced granule copy (nx, dw) --------
    const float* nxsrc = nx   + (size_t)e0 * 260;
    const float* dwsrc = dwei + (size_t)e0 * 13;
    const int capnx = rem * 260;
    const int capdw = rem * 13;
    float* ldsb = sm + (t >> 6) * 256;   // per-wave uniform base (floats)
    #pragma unroll
    for (int k = 0; k < 18; ++k) {
        const int G = k * 256 + t;       // granule index; LDS float off = G*4
        if (G < NX_GRAN) {
            if (G * 4 < capnx) stage16(nxsrc + (size_t)G * 4, ldsb + k * 1024);
        } else if (G < TOT_GRAN) {
            const int rel = G - NX_GRAN;
            if (rel * 4 < capdw) stage16(dwsrc + (size_t)rel * 4, ldsb + k * 1024);
        }
    }
    if (t < 130) sm[W_N + t] = nmat[t];  // 520B coalesced, reused all block
    __syncthreads();                     // drains vmcnt per wave

    // ---------------- compute: 4 threads per element ---------------------
    const int  eloc = t >> 2;
    const int  d    = (t >> 1) & 1;      // spatial dim (stiffness)
    const int  h    = t & 1;             // g-parity (stiffness)
    const int  q    = t & 3;             // g-stride-4 slot (mass, epilogue)
    const long e    = e0 + eloc;
    const bool live = eloc < rem;
    const long ee   = live ? e : (long)(nele - 1);   // clamp for global reads

    const float kk  = kp[0];
    const float idt = 1.0f / dtp[0];

    const float* smnx = sm + eloc * 260 + d * 130;
    const float* smdw = sm + W_DW + eloc * 13;
    const float* smn  = sm + W_N;

    float civ[NLOC], dif[NLOC];
    {
        const vf2* ci2 = reinterpret_cast<const vf2*>(cig + (size_t)ee * 10);
        const vf2* cn2 = reinterpret_cast<const vf2*>(cng + (size_t)ee * 10);
        #pragma unroll
        for (int u2 = 0; u2 < 5; ++u2) {
            vf2 a = ci2[u2], b = cn2[u2];
            civ[2*u2]   = a.x; civ[2*u2+1] = a.y;
            dif[2*u2]   = b.x - a.x; dif[2*u2+1] = b.y - a.y;
        }
    }

    float acc[NPAIR];
    #pragma unroll
    for (int p = 0; p < NPAIR; ++p) acc[p] = 0.0f;
    float r0a[NLOC];
    #pragma unroll
    for (int i = 0; i < NLOC; ++i) r0a[i] = 0.0f;

    // stiffness: this thread's dim d, g = 2*it + h (7 iters, last guarded)
    #pragma unroll
    for (int it = 0; it < 7; ++it) {
        const int   graw = 2 * it + h;
        const int   g    = graw < NGI ? graw : NGI - 1;
        const float wv   = graw < NGI ? kk * smdw[g] : 0.0f;
        float col[NLOC];
        #pragma unroll
        for (int l = 0; l < NLOC; ++l) col[l] = smnx[l * 13 + g];
        float u = 0.0f;
        #pragma unroll
        for (int l = 0; l < NLOC; ++l) u = fmaf(col[l], civ[l], u);
        const float uw = u * wv;
        #pragma unroll
        for (int i = 0; i < NLOC; ++i) {
            const float ti = col[i] * wv;
            #pragma unroll
            for (int j = i; j < NLOC; ++j)
                acc[pidx(i, j)] = fmaf(ti, col[j], acc[pidx(i, j)]);
            r0a[i] = fmaf(-col[i], uw, r0a[i]);
        }
    }

    // mass: g = q + 4*it (4 iters, guarded); weight idt*dw; r0 += nn/dt*(cn-ci)
    #pragma unroll
    for (int it = 0; it < 4; ++it) {
        const int   graw = q + 4 * it;
        const int   g    = graw < NGI ? graw : NGI - 1;
        const float wv   = graw < NGI ? idt * smdw[g] : 0.0f;
        float ncol[NLOC];
        #pragma unroll
        for (int l = 0; l < NLOC; ++l) ncol[l] = smn[l * 13 + g];
        float wd = 0.0f;
        #pragma unroll
        for (int l = 0; l < NLOC; ++l) wd = fmaf(ncol[l], dif[l], wd);
        #pragma unroll
        for (int i = 0; i < NLOC; ++i) {
            const float ti = ncol[i] * wv;
            #pragma unroll
            for (int j = i; j < NLOC; ++j)
                acc[pidx(i, j)] = fmaf(ti, ncol[j], acc[pidx(i, j)]);
            r0a[i] = fmaf(ti, wd, r0a[i]);
        }
    }

    // combine the 4 partial sums: DPP quad butterfly (VALU, no LDS traffic)
    #pragma unroll
    for (int p = 0; p < NPAIR; ++p) {
        acc[p] += qperm<0xB1>(acc[p]);
        acc[p] += qperm<0x4E>(acc[p]);
    }
    #pragma unroll
    for (int i = 0; i < NLOC; ++i) {
        r0a[i] += qperm<0xB1>(r0a[i]);
        r0a[i] += qperm<0x4E>(r0a[i]);
    }

    // ---------------- epilogue: rows split by (i&3)==q, literal indices --
    if (live) {
        float* obd = out + (size_t)e * 100;
        float* odg = out + (size_t)nele * 100 + (size_t)e * 10;
        float* oro = out + (size_t)nele * 110 + (size_t)e * 10;
        const float* r0s = r0g + (size_t)e * 10;
        #pragma unroll
        for (int i = 0; i < NLOC; ++i) {
            if ((i & 3) == q) {
                float row[NLOC];
                #pragma unroll
                for (int j = 0; j < NLOC; ++j) {
                    const int lo = i < j ? i : j, hi = i < j ? j : i;
                    row[j] = acc[pidx(lo, hi)];
                }
                #pragma unroll
                for (int u2 = 0; u2 < 5; ++u2) {
                    vf2 v = { row[2*u2], row[2*u2+1] };
                    *reinterpret_cast<vf2*>(obd + i * 10 + 2 * u2) = v;
                }
                odg[i] = row[i];
                oro[i] = r0s[i] + r0a[i];
            }
        }
    }
}

extern "C" void kernel_launch(void* const* d_in, const int* in_sizes, int n_in,
                              void* d_out, int out_size, void* d_ws, size_t ws_size,
                              hipStream_t stream) {
    const float* r0   = (const float*)d_in[0];
    const float* ci   = (const float*)d_in[1];
    const float* cn   = (const float*)d_in[2];
    const float* k    = (const float*)d_in[3];
    const float* dt   = (const float*)d_in[4];
    const float* nmat = (const float*)d_in[5];
    const float* nx   = (const float*)d_in[6];
    const float* dw   = (const float*)d_in[7];
    const int nele = in_sizes[7] / NGI;

    const int nb = (nele + EPB - 1) / EPB;
    fem_kernel<<<nb, TPB, 0, stream>>>(r0, ci, cn, k, dt, nmat, nx, dw,
                                       (float*)d_out, nele);
}